// Round 12
// baseline (232.380 us; speedup 1.0000x reference)
//
#include <hip/hip_runtime.h>

namespace {
constexpr int Hn = 512, Wn = 512;
constexpr int WHn = 227, WWn = 227;
constexpr int OHn = 285, OWn = 285;   // valid stat grid
constexpr int PTn = 113, PLn = 113;   // replicate-pad offsets
constexpr float EPSn = 1e-5f;
constexpr int NSEG = 17, NSLOT = 9;
// 17 disjoint row segments (inclusive) from the boundaries {h0+1,h0+228}
// of the 9 windows h0 in {0,36,72,108,144,180,216,252,284}
__device__ __constant__ int kSegA[NSEG] =
    {1,37,73,109,145,181,217,228,253,264,285,300,336,372,408,444,480};
__device__ __constant__ int kSegB[NSEG] =
    {36,72,108,144,180,216,227,252,263,284,299,335,371,407,443,479,511};
// window slot k = sum of segments kWinLo[k]..kWinHi[k]
// slots 0..7 = chunk starts h0=36c; slot 8 = w(284) (bottom border)
__device__ __constant__ int kWinLo[NSLOT] = {0,1,2,3,4,5,6,8,10};
__device__ __constant__ int kWinHi[NSLOT] = {6,8,10,11,12,13,14,15,16};
// border-row shares: chunks 0-3 top rows 0..112, chunks 4-7 bottom 398..511
__device__ __constant__ int kBr0[8] = {0,29,57,85,398,427,456,484};
__device__ __constant__ int kBrN[8] = {29,28,28,28,29,29,28,28};
}

// K1: per (group, 128-col strip): 17 disjoint segment sums of (S,Q) per
// column (each x row read ONCE), composed into 9 window snapshots in ws.
// Thread = (quad q2 of 32, row-phase p of 16); per-segment LDS transpose.
__global__ __launch_bounds__(512, 4) void lcn_snap(const float* __restrict__ x,
                                                   float2* __restrict__ snap) {
  const int B = blockIdx.x;
  const int g = B >> 2;              // 0..127
  const int st = B & 3;              // column strip (128 cols)
  const int w = threadIdx.x;
  const int q2 = w & 31;
  const int p = w >> 5;

  const float4* __restrict__ b0 =
      reinterpret_cast<const float4*>(x + (size_t)(g * 2) * Hn * Wn) + st * 32 + q2;
  const float4* __restrict__ b1 = b0 + (size_t)Hn * (Wn / 4);

  __shared__ float4 tbuf[16][64];        // 16 KB transpose buffer
  __shared__ float2 segLds[NSEG][128];   // 17.4 KB per-col segment sums

  for (int s = 0; s < NSEG; ++s) {
    float4 aS = {0.f,0.f,0.f,0.f}, aQ = {0.f,0.f,0.f,0.f};
    for (int r = kSegA[s] + p; r <= kSegB[s]; r += 16) {
      float4 a = b0[(size_t)r * (Wn / 4)];
      float4 b = b1[(size_t)r * (Wn / 4)];
      aS.x += a.x + b.x; aQ.x += a.x * a.x + b.x * b.x;
      aS.y += a.y + b.y; aQ.y += a.y * a.y + b.y * b.y;
      aS.z += a.z + b.z; aQ.z += a.z * a.z + b.z * b.z;
      aS.w += a.w + b.w; aQ.w += a.w * a.w + b.w * b.w;
    }
    __syncthreads();   // prior transpose reads done before rewriting tbuf
    tbuf[p][2 * q2]     = make_float4(aS.x, aQ.x, aS.y, aQ.y);
    tbuf[p][2 * q2 + 1] = make_float4(aS.z, aQ.z, aS.w, aQ.w);
    __syncthreads();
    if (w < 128) {
      const float2* cf = reinterpret_cast<const float2*>(&tbuf[0][0]);
      float2 acc = {0.f, 0.f};
      #pragma unroll
      for (int pp = 0; pp < 16; ++pp) {
        float2 t = cf[pp * 128 + w];
        acc.x += t.x; acc.y += t.y;
      }
      segLds[s][w] = acc;   // col sum for strip-col w
    }
  }
  __syncthreads();
  if (w < 128) {
    for (int k = 0; k < NSLOT; ++k) {
      float2 acc = {0.f, 0.f};
      for (int i = kWinLo[k]; i <= kWinHi[k]; ++i) {
        acc.x += segLds[i][w].x; acc.y += segLds[i][w].y;
      }
      snap[((size_t)g * NSLOT + k) * 512 + st * 128 + w] = acc;
    }
  }
}

// K2: fused slide+scan+normalize. 1024 blocks = (XCD, group, chunk of 8);
// 36 stat rows per chunk (chunk 7: 33). 4-row double-buffered iterations,
// LDS ~33 KB -> 4 blocks/CU (occupancy was the round-8/11 cap).
// Phase B: f32 vertical slide + 512-wide scan -> window sums in Ps[buf];
//          normalize out rows hh = stat+113 directly.
// Phase C: every chunk streams ~28 border rows; border stats recomputed
//          from snapshot (slot 0 top / slot 8 bottom) with one extra scan.
// Window for stat (h,w): input rows h+1..h+227, cols w+1..w+227.
__global__ __launch_bounds__(512, 8) void lcn_fused(const float* __restrict__ x,
                                                    const float* __restrict__ weight,
                                                    const float* __restrict__ bias,
                                                    const float2* __restrict__ snap,
                                                    float* __restrict__ out) {
  const int B = blockIdx.x;
  const int X = B & 7;               // XCD (round-robin heuristic)
  const int s = B >> 3;              // 0..127
  const int chunk = s & 7;
  const int g = X * 16 + (s >> 3);   // all 8 chunks of a group co-XCD
  const int w = threadIdx.x;
  const int lane = w & 63;
  const int wid = w >> 6;

  const float* __restrict__ x0 = x + (size_t)(g * 2) * Hn * Wn;
  const float* __restrict__ x1 = x0 + (size_t)Hn * Wn;
  float* __restrict__ o0 = out + (size_t)(g * 2) * Hn * Wn;
  float* __restrict__ o1 = o0 + (size_t)Hn * Wn;
  // weight/bias: 32 entries, index by channel within image (round-6 bug).
  const int cch = (g & 15) * 2;
  const float wt0 = weight[cch], wt1 = weight[cch + 1];
  const float bs0 = bias[cch], bs1 = bias[cch + 1];

  const int h0 = chunk * 36;
  const int h1 = min(OHn, h0 + 36);

  __shared__ __align__(16) float2 Ps[2][4][Wn + 1];  // 32.8 KB double-buffer
  __shared__ float2 wsum[8][4];

  // chunk-start + border windows from the snapshot
  const float2 sv = snap[((size_t)g * NSLOT + chunk) * 512 + w];
  float accS = sv.x, accQ = sv.y;
  const int bslot = (chunk < 4) ? 0 : 8;
  const float2 bv = snap[((size_t)g * NSLOT + bslot) * 512 + w];

  const float inv_n = 1.0f / (float)(WHn * WWn * 2);
  const int wp = min(max(w - PLn, 0), OWn - 1);   // out-col -> stat-col

  // slide prefetch: add rows h+228+j, sub rows h+1+j (j=0..3), 2 channels
  float pa0[4], pa1[4], ps0[4], ps1[4];
  auto prefetch = [&](int hb) {
    #pragma unroll
    for (int j = 0; j < 4; ++j) {
      int ra = min(hb + WHn + 1 + j, Hn - 1);   // clamp: guarded rows unused
      int rs = hb + 1 + j;                      // max 288 < 512
      pa0[j] = x0[(size_t)ra * Wn + w];
      pa1[j] = x1[(size_t)ra * Wn + w];
      ps0[j] = x0[(size_t)rs * Wn + w];
      ps1[j] = x1[(size_t)rs * Wn + w];
    }
  };
  prefetch(h0);

  // ---- Phase B: slide + scan + fused normalize, 4 rows/iter ----
  int buf = 0;
  for (int h = h0; h < h1; h += 4) {
    float2 v[4];
    v[0] = make_float2(accS, accQ);
    float s2 = accS, q2 = accQ;
    #pragma unroll
    for (int j = 0; j < 3; ++j) {
      s2 += (pa0[j] + pa1[j]) - (ps0[j] + ps1[j]);
      q2 += (pa0[j] * pa0[j] + pa1[j] * pa1[j])
          - (ps0[j] * ps0[j] + ps1[j] * ps1[j]);
      v[j + 1] = make_float2(s2, q2);
    }
    s2 += (pa0[3] + pa1[3]) - (ps0[3] + ps1[3]);
    q2 += (pa0[3] * pa0[3] + pa1[3] * pa1[3])
        - (ps0[3] * ps0[3] + ps1[3] * ps1[3]);
    accS = s2; accQ = q2;

    // next slide loads + this iteration's norm-x loads, hidden under scan
    if (h + 4 < h1) prefetch(h + 4);
    float xa[4], xb[4];
    #pragma unroll
    for (int rr = 0; rr < 4; ++rr) {
      const size_t hh = (size_t)(h + PTn + rr) * Wn + w;  // max row 400 < 512
      xa[rr] = x0[hh];
      xb[rr] = x1[hh];
    }

    // 4 independent 512-wide inclusive scans (shared barriers)
    #pragma unroll
    for (int d = 1; d < 64; d <<= 1) {
      #pragma unroll
      for (int rr = 0; rr < 4; ++rr) {
        float sx = __shfl_up(v[rr].x, d, 64);
        float sy = __shfl_up(v[rr].y, d, 64);
        if (lane >= d) { v[rr].x += sx; v[rr].y += sy; }
      }
    }
    if (lane == 63) {
      #pragma unroll
      for (int rr = 0; rr < 4; ++rr) wsum[wid][rr] = v[rr];
    }
    __syncthreads();
    float2 off[4] = {{0.f,0.f},{0.f,0.f},{0.f,0.f},{0.f,0.f}};
    #pragma unroll
    for (int i = 0; i < 7; ++i) {
      if (i < wid) {
        #pragma unroll
        for (int rr = 0; rr < 4; ++rr) {
          off[rr].x += wsum[i][rr].x; off[rr].y += wsum[i][rr].y;
        }
      }
    }
    #pragma unroll
    for (int rr = 0; rr < 4; ++rr)
      Ps[buf][rr][w + 1] = make_float2(v[rr].x + off[rr].x, v[rr].y + off[rr].y);
    __syncthreads();

    // fused normalize: out row hh = (h+rr)+113 from stat row h+rr
    #pragma unroll
    for (int rr = 0; rr < 4; ++rr) {
      if (h + rr < h1) {
        float2 hi = Ps[buf][rr][wp + WWn + 1];
        float2 lo = Ps[buf][rr][wp + 1];
        float S = hi.x - lo.x;
        float Q = hi.y - lo.y;
        float mean = S * inv_n;
        float var = (Q - S * S * inv_n) * inv_n;
        float istd = rsqrtf(var + EPSn);
        const size_t oo = (size_t)(h + PTn + rr) * Wn + w;
        o0[oo] = (xa[rr] - mean) * istd * wt0 + bs0;
        o1[oo] = (xb[rr] - mean) * istd * wt1 + bs1;
      }
    }
    buf ^= 1;
  }

  // ---- Phase C: border stats (one scan from snapshot) + border stream ----
  __syncthreads();   // main-loop Ps reads done before reuse
  {
    float2 v = bv;
    #pragma unroll
    for (int d = 1; d < 64; d <<= 1) {
      float sx = __shfl_up(v.x, d, 64);
      float sy = __shfl_up(v.y, d, 64);
      if (lane >= d) { v.x += sx; v.y += sy; }
    }
    if (lane == 63) wsum[wid][0] = v;
    __syncthreads();
    float2 off = {0.f, 0.f};
    #pragma unroll
    for (int i = 0; i < 7; ++i) {
      if (i < wid) { off.x += wsum[i][0].x; off.y += wsum[i][0].y; }
    }
    Ps[0][0][w + 1] = make_float2(v.x + off.x, v.y + off.y);
    __syncthreads();
    float2 hi = Ps[0][0][wp + WWn + 1];
    float2 lo = Ps[0][0][wp + 1];
    float S = hi.x - lo.x;
    float Q = hi.y - lo.y;
    float mean = S * inv_n;
    float var = (Q - S * S * inv_n) * inv_n;
    float istd = rsqrtf(var + EPSn);
    Ps[0][1][w] = make_float2(mean, istd);   // bst[out-col]
    __syncthreads();
  }
  {
    const float2* bst = &Ps[0][1][0];
    const int row0 = kBr0[chunk];
    const int total = kBrN[chunk] * 256;               // 2 ch x 128 quads
    const float4* __restrict__ xf0 = reinterpret_cast<const float4*>(x0);
    const float4* __restrict__ xf1 = reinterpret_cast<const float4*>(x1);
    float4* __restrict__ of0 = reinterpret_cast<float4*>(o0);
    float4* __restrict__ of1 = reinterpret_cast<float4*>(o1);
    for (int i = w; i < total; i += 512) {
      const int qq = i & 127;
      const int ch = (i >> 7) & 1;
      const int row = row0 + (i >> 8);
      const size_t idx = (size_t)row * (Wn / 4) + qq;
      const float4 xv = ch ? xf1[idx] : xf0[idx];
      const float wt = ch ? wt1 : wt0;
      const float bsv = ch ? bs1 : bs0;
      const float2 m0 = bst[4 * qq + 0];
      const float2 m1 = bst[4 * qq + 1];
      const float2 m2 = bst[4 * qq + 2];
      const float2 m3 = bst[4 * qq + 3];
      float4 ov;
      ov.x = (xv.x - m0.x) * m0.y * wt + bsv;
      ov.y = (xv.y - m1.x) * m1.y * wt + bsv;
      ov.z = (xv.z - m2.x) * m2.y * wt + bsv;
      ov.w = (xv.w - m3.x) * m3.y * wt + bsv;
      if (ch) of1[idx] = ov; else of0[idx] = ov;
    }
  }
}

extern "C" void kernel_launch(void* const* d_in, const int* in_sizes, int n_in,
                              void* d_out, int out_size, void* d_ws, size_t ws_size,
                              hipStream_t stream) {
  const float* x = (const float*)d_in[0];
  const float* weight = (const float*)d_in[1];
  const float* bias = (const float*)d_in[2];
  float* out = (float*)d_out;
  float2* snap = (float2*)d_ws;   // 128*9*512*8 B = 4.7 MB (ws is larger)

  hipLaunchKernelGGL(lcn_snap, dim3(512), dim3(512), 0, stream, x, snap);
  hipLaunchKernelGGL(lcn_fused, dim3(1024), dim3(512), 0, stream,
                     x, weight, bias, snap, out);
}

// Round 13
// 180.844 us; speedup vs baseline: 1.2850x; 1.2850x over previous
//
#include <hip/hip_runtime.h>

namespace {
constexpr int Hn = 512, Wn = 512;
constexpr int WHn = 227, WWn = 227;
constexpr int OHn = 285, OWn = 285;   // valid stat grid
constexpr int PTn = 113, PLn = 113;   // replicate-pad offsets
constexpr float EPSn = 1e-5f;
constexpr int NSEG = 17, NSLOT = 9;
// 17 disjoint row segments (inclusive) from the boundaries {h0+1,h0+228}
// of the 9 windows h0 in {0,36,72,108,144,180,216,252,284}
__device__ __constant__ int kSegA[NSEG] =
    {1,37,73,109,145,181,217,228,253,264,285,300,336,372,408,444,480};
__device__ __constant__ int kSegB[NSEG] =
    {36,72,108,144,180,216,227,252,263,284,299,335,371,407,443,479,511};
// window slot k = sum of segments kWinLo[k]..kWinHi[k]
// slots 0..7 = chunk starts h0=36c; slot 8 = w(284) (bottom border)
__device__ __constant__ int kWinLo[NSLOT] = {0,1,2,3,4,5,6,8,10};
__device__ __constant__ int kWinHi[NSLOT] = {6,8,10,11,12,13,14,15,16};
// border-row shares: chunks 0-3 top rows 0..112, chunks 4-7 bottom 398..511
__device__ __constant__ int kBr0[8] = {0,29,57,85,398,427,456,484};
__device__ __constant__ int kBrN[8] = {29,28,28,28,29,29,28,28};
}

// K1: per (group, 128-col strip): 17 disjoint segment sums of (S,Q) per
// column (each x row read ONCE), composed into 9 window snapshots in ws.
// Thread = (quad q2 of 32, row-phase p of 16); per-segment LDS transpose.
__global__ __launch_bounds__(512, 4) void lcn_snap(const float* __restrict__ x,
                                                   float2* __restrict__ snap) {
  const int B = blockIdx.x;
  const int g = B >> 2;              // 0..127
  const int st = B & 3;              // column strip (128 cols)
  const int w = threadIdx.x;
  const int q2 = w & 31;
  const int p = w >> 5;

  const float4* __restrict__ b0 =
      reinterpret_cast<const float4*>(x + (size_t)(g * 2) * Hn * Wn) + st * 32 + q2;
  const float4* __restrict__ b1 = b0 + (size_t)Hn * (Wn / 4);

  __shared__ float4 tbuf[16][64];        // 16 KB transpose buffer
  __shared__ float2 segLds[NSEG][128];   // 17.4 KB per-col segment sums

  for (int s = 0; s < NSEG; ++s) {
    float4 aS = {0.f,0.f,0.f,0.f}, aQ = {0.f,0.f,0.f,0.f};
    for (int r = kSegA[s] + p; r <= kSegB[s]; r += 16) {
      float4 a = b0[(size_t)r * (Wn / 4)];
      float4 b = b1[(size_t)r * (Wn / 4)];
      aS.x += a.x + b.x; aQ.x += a.x * a.x + b.x * b.x;
      aS.y += a.y + b.y; aQ.y += a.y * a.y + b.y * b.y;
      aS.z += a.z + b.z; aQ.z += a.z * a.z + b.z * b.z;
      aS.w += a.w + b.w; aQ.w += a.w * a.w + b.w * b.w;
    }
    __syncthreads();   // prior transpose reads done before rewriting tbuf
    tbuf[p][2 * q2]     = make_float4(aS.x, aQ.x, aS.y, aQ.y);
    tbuf[p][2 * q2 + 1] = make_float4(aS.z, aQ.z, aS.w, aQ.w);
    __syncthreads();
    if (w < 128) {
      const float2* cf = reinterpret_cast<const float2*>(&tbuf[0][0]);
      float2 acc = {0.f, 0.f};
      #pragma unroll
      for (int pp = 0; pp < 16; ++pp) {
        float2 t = cf[pp * 128 + w];
        acc.x += t.x; acc.y += t.y;
      }
      segLds[s][w] = acc;   // col sum for strip-col w
    }
  }
  __syncthreads();
  if (w < 128) {
    for (int k = 0; k < NSLOT; ++k) {
      float2 acc = {0.f, 0.f};
      for (int i = kWinLo[k]; i <= kWinHi[k]; ++i) {
        acc.x += segLds[i][w].x; acc.y += segLds[i][w].y;
      }
      snap[((size_t)g * NSLOT + k) * 512 + st * 128 + w] = acc;
    }
  }
}

// K2: fused slide+scan+normalize. 1024 blocks = (XCD, group, chunk of 8);
// 36 stat rows per chunk (chunk 7: 33). 4-row double-buffered iterations,
// LDS ~33 KB. launch_bounds(512,4): round-12's (512,8) forced VGPR=32 ->
// scratch spill (WRITE 265->387 MB); (512,4) lets the allocator hold ~56
// VGPR, and if <=64 we still reach 4 blocks/CU (LDS also allows 4).
// Phase B: f32 vertical slide + 512-wide scan -> window sums in Ps[buf];
//          normalize out rows hh = stat+113 directly.
// Phase C: every chunk streams ~28 border rows; border stats recomputed
//          from snapshot (slot 0 top / slot 8 bottom) with one extra scan.
// Window for stat (h,w): input rows h+1..h+227, cols w+1..w+227.
__global__ __launch_bounds__(512, 4) void lcn_fused(const float* __restrict__ x,
                                                    const float* __restrict__ weight,
                                                    const float* __restrict__ bias,
                                                    const float2* __restrict__ snap,
                                                    float* __restrict__ out) {
  const int B = blockIdx.x;
  const int X = B & 7;               // XCD (round-robin heuristic)
  const int s = B >> 3;              // 0..127
  const int chunk = s & 7;
  const int g = X * 16 + (s >> 3);   // all 8 chunks of a group co-XCD
  const int w = threadIdx.x;
  const int lane = w & 63;
  const int wid = w >> 6;

  const float* __restrict__ x0 = x + (size_t)(g * 2) * Hn * Wn;
  const float* __restrict__ x1 = x0 + (size_t)Hn * Wn;
  float* __restrict__ o0 = out + (size_t)(g * 2) * Hn * Wn;
  float* __restrict__ o1 = o0 + (size_t)Hn * Wn;
  // weight/bias: 32 entries, index by channel within image (round-6 bug).
  const int cch = (g & 15) * 2;
  const float wt0 = weight[cch], wt1 = weight[cch + 1];
  const float bs0 = bias[cch], bs1 = bias[cch + 1];

  const int h0 = chunk * 36;
  const int h1 = min(OHn, h0 + 36);

  __shared__ __align__(16) float2 Ps[2][4][Wn + 1];  // 32.8 KB double-buffer
  __shared__ float2 wsum[8][4];

  // chunk-start + border windows from the snapshot
  const float2 sv = snap[((size_t)g * NSLOT + chunk) * 512 + w];
  float accS = sv.x, accQ = sv.y;
  const int bslot = (chunk < 4) ? 0 : 8;
  const float2 bv = snap[((size_t)g * NSLOT + bslot) * 512 + w];

  const float inv_n = 1.0f / (float)(WHn * WWn * 2);
  const int wp = min(max(w - PLn, 0), OWn - 1);   // out-col -> stat-col

  // slide prefetch: add rows h+228+j, sub rows h+1+j (j=0..3), 2 channels
  float pa0[4], pa1[4], ps0[4], ps1[4];
  auto prefetch = [&](int hb) {
    #pragma unroll
    for (int j = 0; j < 4; ++j) {
      int ra = min(hb + WHn + 1 + j, Hn - 1);   // clamp: guarded rows unused
      int rs = hb + 1 + j;                      // max 288 < 512
      pa0[j] = x0[(size_t)ra * Wn + w];
      pa1[j] = x1[(size_t)ra * Wn + w];
      ps0[j] = x0[(size_t)rs * Wn + w];
      ps1[j] = x1[(size_t)rs * Wn + w];
    }
  };
  prefetch(h0);

  // ---- Phase B: slide + scan + fused normalize, 4 rows/iter ----
  int buf = 0;
  for (int h = h0; h < h1; h += 4) {
    float2 v[4];
    v[0] = make_float2(accS, accQ);
    float s2 = accS, q2 = accQ;
    #pragma unroll
    for (int j = 0; j < 3; ++j) {
      s2 += (pa0[j] + pa1[j]) - (ps0[j] + ps1[j]);
      q2 += (pa0[j] * pa0[j] + pa1[j] * pa1[j])
          - (ps0[j] * ps0[j] + ps1[j] * ps1[j]);
      v[j + 1] = make_float2(s2, q2);
    }
    s2 += (pa0[3] + pa1[3]) - (ps0[3] + ps1[3]);
    q2 += (pa0[3] * pa0[3] + pa1[3] * pa1[3])
        - (ps0[3] * ps0[3] + ps1[3] * ps1[3]);
    accS = s2; accQ = q2;

    // next slide loads + this iteration's norm-x loads, hidden under scan
    if (h + 4 < h1) prefetch(h + 4);
    float xa[4], xb[4];
    #pragma unroll
    for (int rr = 0; rr < 4; ++rr) {
      const size_t hh = (size_t)(h + PTn + rr) * Wn + w;  // max row 400 < 512
      xa[rr] = x0[hh];
      xb[rr] = x1[hh];
    }

    // 4 independent 512-wide inclusive scans (shared barriers)
    #pragma unroll
    for (int d = 1; d < 64; d <<= 1) {
      #pragma unroll
      for (int rr = 0; rr < 4; ++rr) {
        float sx = __shfl_up(v[rr].x, d, 64);
        float sy = __shfl_up(v[rr].y, d, 64);
        if (lane >= d) { v[rr].x += sx; v[rr].y += sy; }
      }
    }
    if (lane == 63) {
      #pragma unroll
      for (int rr = 0; rr < 4; ++rr) wsum[wid][rr] = v[rr];
    }
    __syncthreads();
    float2 off[4] = {{0.f,0.f},{0.f,0.f},{0.f,0.f},{0.f,0.f}};
    #pragma unroll
    for (int i = 0; i < 7; ++i) {
      if (i < wid) {
        #pragma unroll
        for (int rr = 0; rr < 4; ++rr) {
          off[rr].x += wsum[i][rr].x; off[rr].y += wsum[i][rr].y;
        }
      }
    }
    #pragma unroll
    for (int rr = 0; rr < 4; ++rr)
      Ps[buf][rr][w + 1] = make_float2(v[rr].x + off[rr].x, v[rr].y + off[rr].y);
    __syncthreads();

    // fused normalize: out row hh = (h+rr)+113 from stat row h+rr
    #pragma unroll
    for (int rr = 0; rr < 4; ++rr) {
      if (h + rr < h1) {
        float2 hi = Ps[buf][rr][wp + WWn + 1];
        float2 lo = Ps[buf][rr][wp + 1];
        float S = hi.x - lo.x;
        float Q = hi.y - lo.y;
        float mean = S * inv_n;
        float var = (Q - S * S * inv_n) * inv_n;
        float istd = rsqrtf(var + EPSn);
        const size_t oo = (size_t)(h + PTn + rr) * Wn + w;
        o0[oo] = (xa[rr] - mean) * istd * wt0 + bs0;
        o1[oo] = (xb[rr] - mean) * istd * wt1 + bs1;
      }
    }
    buf ^= 1;
  }

  // ---- Phase C: border stats (one scan from snapshot) + border stream ----
  __syncthreads();   // main-loop Ps reads done before reuse
  {
    float2 v = bv;
    #pragma unroll
    for (int d = 1; d < 64; d <<= 1) {
      float sx = __shfl_up(v.x, d, 64);
      float sy = __shfl_up(v.y, d, 64);
      if (lane >= d) { v.x += sx; v.y += sy; }
    }
    if (lane == 63) wsum[wid][0] = v;
    __syncthreads();
    float2 off = {0.f, 0.f};
    #pragma unroll
    for (int i = 0; i < 7; ++i) {
      if (i < wid) { off.x += wsum[i][0].x; off.y += wsum[i][0].y; }
    }
    Ps[0][0][w + 1] = make_float2(v.x + off.x, v.y + off.y);
    __syncthreads();
    float2 hi = Ps[0][0][wp + WWn + 1];
    float2 lo = Ps[0][0][wp + 1];
    float S = hi.x - lo.x;
    float Q = hi.y - lo.y;
    float mean = S * inv_n;
    float var = (Q - S * S * inv_n) * inv_n;
    float istd = rsqrtf(var + EPSn);
    Ps[0][1][w] = make_float2(mean, istd);   // bst[out-col]
    __syncthreads();
  }
  {
    const float2* bst = &Ps[0][1][0];
    const int row0 = kBr0[chunk];
    const int total = kBrN[chunk] * 256;               // 2 ch x 128 quads
    const float4* __restrict__ xf0 = reinterpret_cast<const float4*>(x0);
    const float4* __restrict__ xf1 = reinterpret_cast<const float4*>(x1);
    float4* __restrict__ of0 = reinterpret_cast<float4*>(o0);
    float4* __restrict__ of1 = reinterpret_cast<float4*>(o1);
    for (int i = w; i < total; i += 512) {
      const int qq = i & 127;
      const int ch = (i >> 7) & 1;
      const int row = row0 + (i >> 8);
      const size_t idx = (size_t)row * (Wn / 4) + qq;
      const float4 xv = ch ? xf1[idx] : xf0[idx];
      const float wt = ch ? wt1 : wt0;
      const float bsv = ch ? bs1 : bs0;
      const float2 m0 = bst[4 * qq + 0];
      const float2 m1 = bst[4 * qq + 1];
      const float2 m2 = bst[4 * qq + 2];
      const float2 m3 = bst[4 * qq + 3];
      float4 ov;
      ov.x = (xv.x - m0.x) * m0.y * wt + bsv;
      ov.y = (xv.y - m1.x) * m1.y * wt + bsv;
      ov.z = (xv.z - m2.x) * m2.y * wt + bsv;
      ov.w = (xv.w - m3.x) * m3.y * wt + bsv;
      if (ch) of1[idx] = ov; else of0[idx] = ov;
    }
  }
}

extern "C" void kernel_launch(void* const* d_in, const int* in_sizes, int n_in,
                              void* d_out, int out_size, void* d_ws, size_t ws_size,
                              hipStream_t stream) {
  const float* x = (const float*)d_in[0];
  const float* weight = (const float*)d_in[1];
  const float* bias = (const float*)d_in[2];
  float* out = (float*)d_out;
  float2* snap = (float2*)d_ws;   // 128*9*512*8 B = 4.7 MB (ws is larger)

  hipLaunchKernelGGL(lcn_snap, dim3(512), dim3(512), 0, stream, x, snap);
  hipLaunchKernelGGL(lcn_fused, dim3(1024), dim3(512), 0, stream,
                     x, weight, bias, snap, out);
}

// Round 14
// 167.954 us; speedup vs baseline: 1.3836x; 1.0767x over previous
//
#include <hip/hip_runtime.h>

namespace {
constexpr int Hn = 512, Wn = 512;
constexpr int WHn = 227, WWn = 227;
constexpr int OHn = 285, OWn = 285;   // valid stat grid
constexpr int PTn = 113, PLn = 113;   // replicate-pad offsets
constexpr float EPSn = 1e-5f;
constexpr int NSEG = 17, NSLOT = 9;
// 17 disjoint row segments (inclusive) from the boundaries {h0+1,h0+228}
// of the 9 windows h0 in {0,36,72,108,144,180,216,252,284}
__device__ __constant__ int kSegA[NSEG] =
    {1,37,73,109,145,181,217,228,253,264,285,300,336,372,408,444,480};
__device__ __constant__ int kSegB[NSEG] =
    {36,72,108,144,180,216,227,252,263,284,299,335,371,407,443,479,511};
// window slot k = sum of segments kWinLo[k]..kWinHi[k]
// slots 0..7 = chunk starts h0=36c; slot 8 = w(284) (bottom border)
__device__ __constant__ int kWinLo[NSLOT] = {0,1,2,3,4,5,6,8,10};
__device__ __constant__ int kWinHi[NSLOT] = {6,8,10,11,12,13,14,15,16};
}

// K1: per (group, 128-col strip): 17 disjoint segment sums of (S,Q) per
// column (each x row read ONCE), composed into 9 window snapshots in ws.
// Thread = (quad q2 of 32, row-phase p of 16); per-segment LDS transpose.
// r-loop double-steps (r, r+16) -> 4 global loads in flight per thread.
__global__ __launch_bounds__(512, 4) void lcn_snap(const float* __restrict__ x,
                                                   float2* __restrict__ snap) {
  const int B = blockIdx.x;
  const int g = B >> 2;              // 0..127
  const int st = B & 3;              // column strip (128 cols)
  const int w = threadIdx.x;
  const int q2 = w & 31;
  const int p = w >> 5;

  const float4* __restrict__ b0 =
      reinterpret_cast<const float4*>(x + (size_t)(g * 2) * Hn * Wn) + st * 32 + q2;
  const float4* __restrict__ b1 = b0 + (size_t)Hn * (Wn / 4);

  __shared__ float4 tbuf[16][64];        // 16 KB transpose buffer
  __shared__ float2 segLds[NSEG][128];   // 17.4 KB per-col segment sums

  for (int s = 0; s < NSEG; ++s) {
    float4 aS = {0.f,0.f,0.f,0.f}, aQ = {0.f,0.f,0.f,0.f};
    const int rA = kSegA[s] + p, rB = kSegB[s];
    for (int r = rA; r <= rB; r += 32) {
      float4 a = b0[(size_t)r * (Wn / 4)];
      float4 b = b1[(size_t)r * (Wn / 4)];
      const bool sec = (r + 16 <= rB);
      float4 c, d;
      if (sec) {
        c = b0[(size_t)(r + 16) * (Wn / 4)];
        d = b1[(size_t)(r + 16) * (Wn / 4)];
      }
      aS.x += a.x + b.x; aQ.x += a.x * a.x + b.x * b.x;
      aS.y += a.y + b.y; aQ.y += a.y * a.y + b.y * b.y;
      aS.z += a.z + b.z; aQ.z += a.z * a.z + b.z * b.z;
      aS.w += a.w + b.w; aQ.w += a.w * a.w + b.w * b.w;
      if (sec) {
        aS.x += c.x + d.x; aQ.x += c.x * c.x + d.x * d.x;
        aS.y += c.y + d.y; aQ.y += c.y * c.y + d.y * d.y;
        aS.z += c.z + d.z; aQ.z += c.z * c.z + d.z * d.z;
        aS.w += c.w + d.w; aQ.w += c.w * c.w + d.w * d.w;
      }
    }
    __syncthreads();   // prior transpose reads done before rewriting tbuf
    tbuf[p][2 * q2]     = make_float4(aS.x, aQ.x, aS.y, aQ.y);
    tbuf[p][2 * q2 + 1] = make_float4(aS.z, aQ.z, aS.w, aQ.w);
    __syncthreads();
    if (w < 128) {
      const float2* cf = reinterpret_cast<const float2*>(&tbuf[0][0]);
      float2 acc = {0.f, 0.f};
      #pragma unroll
      for (int pp = 0; pp < 16; ++pp) {
        float2 t = cf[pp * 128 + w];
        acc.x += t.x; acc.y += t.y;
      }
      segLds[s][w] = acc;   // col sum for strip-col w
    }
  }
  __syncthreads();
  if (w < 128) {
    for (int k = 0; k < NSLOT; ++k) {
      float2 acc = {0.f, 0.f};
      for (int i = kWinLo[k]; i <= kWinHi[k]; ++i) {
        acc.x += segLds[i][w].x; acc.y += segLds[i][w].y;
      }
      snap[((size_t)g * NSLOT + k) * 512 + st * 128 + w] = acc;
    }
  }
}

// K2: fused slide+scan+normalize. 1024 blocks = (XCD, group, chunk of 8).
// Round-14: border rows fused INTO the slide loop -- top rows 1..112 ARE
// chunks 0-3's slide-sub rows, bottom rows 398..511 ARE chunks 4-7's
// slide-add rows; normalize them from the already-loaded registers with
// border stats (mean_b/istd_b) computed pre-loop from the snapshot.
// Phase C streaming eliminated (~113 MB logical reads saved). Row 0 is
// loaded explicitly by chunk 0. Every out row written by exactly 1 block.
// launch_bounds(512,4): (512,8) forced VGPR=32 -> spill (round-12 lesson).
// Window for stat (h,w): input rows h+1..h+227, cols w+1..w+227.
__global__ __launch_bounds__(512, 4) void lcn_fused(const float* __restrict__ x,
                                                    const float* __restrict__ weight,
                                                    const float* __restrict__ bias,
                                                    const float2* __restrict__ snap,
                                                    float* __restrict__ out) {
  const int B = blockIdx.x;
  const int X = B & 7;               // XCD (round-robin heuristic)
  const int s = B >> 3;              // 0..127
  const int chunk = s & 7;
  const int g = X * 16 + (s >> 3);   // all 8 chunks of a group co-XCD
  const int w = threadIdx.x;
  const int lane = w & 63;
  const int wid = w >> 6;

  const float* __restrict__ x0 = x + (size_t)(g * 2) * Hn * Wn;
  const float* __restrict__ x1 = x0 + (size_t)Hn * Wn;
  float* __restrict__ o0 = out + (size_t)(g * 2) * Hn * Wn;
  float* __restrict__ o1 = o0 + (size_t)Hn * Wn;
  // weight/bias: 32 entries, index by channel within image (round-6 bug).
  const int cch = (g & 15) * 2;
  const float wt0 = weight[cch], wt1 = weight[cch + 1];
  const float bs0 = bias[cch], bs1 = bias[cch + 1];

  const int h0 = chunk * 36;
  const int h1 = min(OHn, h0 + 36);

  __shared__ __align__(16) float2 Ps[2][4][Wn + 1];  // 32.8 KB double-buffer
  __shared__ float2 wsum[8][4];

  // chunk-start + border windows from the snapshot
  const float2 sv = snap[((size_t)g * NSLOT + chunk) * 512 + w];
  float accS = sv.x, accQ = sv.y;
  const int bslot = (chunk < 4) ? 0 : 8;
  const float2 bv = snap[((size_t)g * NSLOT + bslot) * 512 + w];

  const float inv_n = 1.0f / (float)(WHn * WWn * 2);
  const int wp = min(max(w - PLn, 0), OWn - 1);   // out-col -> stat-col

  // ---- border stats pre-scan (slot 0 for top chunks, slot 8 bottom) ----
  float mean_b, istd_b;
  {
    float2 v = bv;
    #pragma unroll
    for (int d = 1; d < 64; d <<= 1) {
      float sx = __shfl_up(v.x, d, 64);
      float sy = __shfl_up(v.y, d, 64);
      if (lane >= d) { v.x += sx; v.y += sy; }
    }
    if (lane == 63) wsum[wid][0] = v;
    __syncthreads();
    float2 off = {0.f, 0.f};
    #pragma unroll
    for (int i = 0; i < 7; ++i) {
      if (i < wid) { off.x += wsum[i][0].x; off.y += wsum[i][0].y; }
    }
    Ps[0][0][w + 1] = make_float2(v.x + off.x, v.y + off.y);
    __syncthreads();
    float2 hi = Ps[0][0][wp + WWn + 1];
    float2 lo = Ps[0][0][wp + 1];
    float S = hi.x - lo.x;
    float Q = hi.y - lo.y;
    mean_b = S * inv_n;
    istd_b = rsqrtf((Q - S * S * inv_n) * inv_n + EPSn);
    // no extra barrier needed: every wave's reads above precede its arrival
    // at the main loop's first __syncthreads, which gates the Ps rewrite.
  }
  if (chunk == 0) {   // out row 0 (read by no slide) -- border stats
    float a = x0[w], b = x1[w];
    o0[w] = (a - mean_b) * istd_b * wt0 + bs0;
    o1[w] = (b - mean_b) * istd_b * wt1 + bs1;
  }

  // slide prefetch: add rows h+228+j, sub rows h+1+j (j=0..3), 2 channels
  float pa0[4], pa1[4], ps0[4], ps1[4];
  auto prefetch = [&](int hb) {
    #pragma unroll
    for (int j = 0; j < 4; ++j) {
      int ra = min(hb + WHn + 1 + j, Hn - 1);   // clamp: guarded rows unused
      int rs = hb + 1 + j;                      // max 288 < 512
      pa0[j] = x0[(size_t)ra * Wn + w];
      pa1[j] = x1[(size_t)ra * Wn + w];
      ps0[j] = x0[(size_t)rs * Wn + w];
      ps1[j] = x1[(size_t)rs * Wn + w];
    }
  };
  prefetch(h0);

  // ---- Phase B: slide + scan + fused normalize + fused border ----
  int buf = 0;
  for (int h = h0; h < h1; h += 4) {
    float2 v[4];
    v[0] = make_float2(accS, accQ);
    float s2 = accS, q2 = accQ;
    #pragma unroll
    for (int j = 0; j < 3; ++j) {
      s2 += (pa0[j] + pa1[j]) - (ps0[j] + ps1[j]);
      q2 += (pa0[j] * pa0[j] + pa1[j] * pa1[j])
          - (ps0[j] * ps0[j] + ps1[j] * ps1[j]);
      v[j + 1] = make_float2(s2, q2);
    }
    s2 += (pa0[3] + pa1[3]) - (ps0[3] + ps1[3]);
    q2 += (pa0[3] * pa0[3] + pa1[3] * pa1[3])
        - (ps0[3] * ps0[3] + ps1[3] * ps1[3]);
    accS = s2; accQ = q2;

    // save border-row x values before prefetch overwrites the registers
    float bb0[4], bb1[4];
    #pragma unroll
    for (int j = 0; j < 4; ++j) {
      bb0[j] = (chunk < 4) ? ps0[j] : pa0[j];
      bb1[j] = (chunk < 4) ? ps1[j] : pa1[j];
    }

    // next slide loads + this iteration's norm-x loads, hidden under scan
    if (h + 4 < h1) prefetch(h + 4);
    float xa[4], xb[4];
    #pragma unroll
    for (int rr = 0; rr < 4; ++rr) {
      const size_t hh = (size_t)(h + PTn + rr) * Wn + w;  // max row 400 < 512
      xa[rr] = x0[hh];
      xb[rr] = x1[hh];
    }

    // 4 independent 512-wide inclusive scans (shared barriers)
    #pragma unroll
    for (int d = 1; d < 64; d <<= 1) {
      #pragma unroll
      for (int rr = 0; rr < 4; ++rr) {
        float sx = __shfl_up(v[rr].x, d, 64);
        float sy = __shfl_up(v[rr].y, d, 64);
        if (lane >= d) { v[rr].x += sx; v[rr].y += sy; }
      }
    }
    if (lane == 63) {
      #pragma unroll
      for (int rr = 0; rr < 4; ++rr) wsum[wid][rr] = v[rr];
    }
    __syncthreads();
    float2 off[4] = {{0.f,0.f},{0.f,0.f},{0.f,0.f},{0.f,0.f}};
    #pragma unroll
    for (int i = 0; i < 7; ++i) {
      if (i < wid) {
        #pragma unroll
        for (int rr = 0; rr < 4; ++rr) {
          off[rr].x += wsum[i][rr].x; off[rr].y += wsum[i][rr].y;
        }
      }
    }
    #pragma unroll
    for (int rr = 0; rr < 4; ++rr)
      Ps[buf][rr][w + 1] = make_float2(v[rr].x + off[rr].x, v[rr].y + off[rr].y);
    __syncthreads();

    // fused normalize: out row hh = (h+rr)+113 from stat row h+rr
    #pragma unroll
    for (int rr = 0; rr < 4; ++rr) {
      if (h + rr < h1) {
        float2 hi = Ps[buf][rr][wp + WWn + 1];
        float2 lo = Ps[buf][rr][wp + 1];
        float S = hi.x - lo.x;
        float Q = hi.y - lo.y;
        float mean = S * inv_n;
        float var = (Q - S * S * inv_n) * inv_n;
        float istd = rsqrtf(var + EPSn);
        const size_t oo = (size_t)(h + PTn + rr) * Wn + w;
        o0[oo] = (xa[rr] - mean) * istd * wt0 + bs0;
        o1[oo] = (xb[rr] - mean) * istd * wt1 + bs1;
      }
    }

    // fused border: top rows (sub) 1..112, bottom rows (add) 398..511
    #pragma unroll
    for (int j = 0; j < 4; ++j) {
      const int r = (chunk < 4) ? (h + 1 + j) : (h + WHn + 1 + j);
      const bool duty = (chunk < 4) ? (r <= 112) : (r >= 398 && r <= 511);
      if (duty) {
        const size_t oo = (size_t)r * Wn + w;
        o0[oo] = (bb0[j] - mean_b) * istd_b * wt0 + bs0;
        o1[oo] = (bb1[j] - mean_b) * istd_b * wt1 + bs1;
      }
    }
    buf ^= 1;
  }
}

extern "C" void kernel_launch(void* const* d_in, const int* in_sizes, int n_in,
                              void* d_out, int out_size, void* d_ws, size_t ws_size,
                              hipStream_t stream) {
  const float* x = (const float*)d_in[0];
  const float* weight = (const float*)d_in[1];
  const float* bias = (const float*)d_in[2];
  float* out = (float*)d_out;
  float2* snap = (float2*)d_ws;   // 128*9*512*8 B = 4.7 MB (ws is larger)

  hipLaunchKernelGGL(lcn_snap, dim3(512), dim3(512), 0, stream, x, snap);
  hipLaunchKernelGGL(lcn_fused, dim3(1024), dim3(512), 0, stream,
                     x, weight, bias, snap, out);
}